// Round 12
// baseline (621.839 us; speedup 1.0000x reference)
//
#include <hip/hip_runtime.h>
#include <cstdint>
#include <cstddef>

#define NN 8192
#define FIN 256
#define FOUT 128
#define SLOPE 0.2f
#define SHIFT 8.0f

typedef float f32x4 __attribute__((ext_vector_type(4)));
typedef __bf16 bf16x8 __attribute__((ext_vector_type(8)));
typedef unsigned int u32x4 __attribute__((ext_vector_type(4)));

__device__ __forceinline__ unsigned short f2bf(float f) {
  return __builtin_bit_cast(unsigned short, (__bf16)f);
}

// ---------------------------------------------------------------------------
// Kernel P: adj (256 MB int32 0/1) -> bitmask (8 MB). Pure HBM stream, the
// only kernel shape proven to eat HBM at rate (grid-stride, no deps).
// Segment = 256 ints; bit L of ballot k = adj[s*256 + 64k + L]  (R4-proven).
// ---------------------------------------------------------------------------
__global__ __launch_bounds__(256) void k_pack(const int* __restrict__ adj,
                                              unsigned long long* __restrict__ mask) {
  const int wid = blockIdx.x * 4 + (threadIdx.x >> 6);
  const int lane = threadIdx.x & 63;
  for (int s = wid; s < (NN * NN / 256); s += 8192) {
    const int* base = adj + (size_t)s * 256;
    int v0 = base[lane];
    int v1 = base[lane + 64];
    int v2 = base[lane + 128];
    int v3 = base[lane + 192];
    unsigned long long b0 = __ballot(v0 != 0);
    unsigned long long b1 = __ballot(v1 != 0);
    unsigned long long b2 = __ballot(v2 != 0);
    unsigned long long b3 = __ballot(v3 != 0);
    if (lane == 0) {
      unsigned long long* q = mask + (size_t)s * 4;
      q[0] = b0; q[1] = b1; q[2] = b2; q[3] = b3;
    }
  }
}

// ---------------------------------------------------------------------------
// Kernel A: h = x @ W (fp32 acc) -> ht[FOUT][NN] bf16 (transposed), plus fused
// s-reductions and exp-factor tables:
//   Etab[2row,2row+1] = (E, E2) = (e^{s1-c}, e^{0.2 s1 - c}),
//     c = leakyrelu(s1 + SHIFT)  (>= row max of leakyrelu(s1+s2))
//   FbfF[j] = bf16(e^{s2_j}),  FbfF2[j] = bf16(e^{0.2 s2_j})
// so exp(leakyrelu(s1+s2) - c) = max(E*F, E2*F2)  (exp monotone, exact).
// ---------------------------------------------------------------------------
__global__ __launch_bounds__(256, 4) void k_hw(const float* __restrict__ x,
                                               const float* __restrict__ W,
                                               const float* __restrict__ a1,
                                               const float* __restrict__ a2,
                                               unsigned short* __restrict__ ht,
                                               float* __restrict__ Etab,
                                               unsigned short* __restrict__ FbfF,
                                               unsigned short* __restrict__ FbfF2) {
  __shared__ float xs[8][256];
  __shared__ unsigned short tile[128][8];   // [f][row]
  const int tid = threadIdx.x;
  const int rowbase = blockIdx.x * 8;

  #pragma unroll
  for (int it = 0; it < 2; ++it) {
    int fi = it * 1024 + tid * 4;
    int r = fi >> 8, k = fi & 255;
    *(f32x4*)&xs[r][k] = *(const f32x4*)(x + (size_t)(rowbase + r) * FIN + k);
  }
  __syncthreads();

  const int r = tid >> 5;    // 0..7
  const int cg = tid & 31;   // cols cg*4..cg*4+3
  f32x4 acc = {0.f, 0.f, 0.f, 0.f};

  #pragma unroll 8
  for (int k = 0; k < FIN; ++k) {
    f32x4 wv = *(const f32x4*)(W + k * FOUT + cg * 4);
    float xv = xs[r][k];
    acc[0] += xv * wv[0];
    acc[1] += xv * wv[1];
    acc[2] += xv * wv[2];
    acc[3] += xv * wv[3];
  }

  #pragma unroll
  for (int c = 0; c < 4; ++c) tile[cg * 4 + c][r] = f2bf(acc[c]);

  f32x4 av1 = *(const f32x4*)(a1 + cg * 4);
  f32x4 av2 = *(const f32x4*)(a2 + cg * 4);
  float s1 = acc[0] * av1[0] + acc[1] * av1[1] + acc[2] * av1[2] + acc[3] * av1[3];
  float s2 = acc[0] * av2[0] + acc[1] * av2[1] + acc[2] * av2[2] + acc[3] * av2[3];
  #pragma unroll
  for (int off = 16; off > 0; off >>= 1) {
    s1 += __shfl_xor(s1, off, 64);
    s2 += __shfl_xor(s2, off, 64);
  }
  if (cg == 0) {
    const int row = rowbase + r;
    float c0 = s1 + SHIFT;
    float c = fmaxf(c0, SLOPE * c0);
    Etab[(size_t)row * 2]     = __expf(s1 - c);
    Etab[(size_t)row * 2 + 1] = __expf(SLOPE * s1 - c);
    FbfF[row]  = f2bf(__expf(s2));
    FbfF2[row] = f2bf(__expf(SLOPE * s2));
  }
  __syncthreads();

  if (tid < 128) {
    u32x4 v = *(const u32x4*)&tile[tid][0];
    *(u32x4*)(ht + (size_t)tid * NN + rowbase) = v;
  }
}

// ---------------------------------------------------------------------------
// Kernel B: fused masked-softmax aggregation, v12.
// ZERO LDS, ZERO barriers, ZERO DMA. 512 blocks x 4 waves; each wave fully
// independent: 16 rows x 2 f-tiles x full j. All inner-loop operands are
// per-thread register loads from cache-hot data (mask 8 MB L3, F/G 32 KB L2,
// ht 2 MB per-XCD L2), DEPTH-1 PREFETCHED THROUGH LOOP-CARRIED PHIs:
// the loop is kept ROLLED (#pragma unroll 1) so the prefetch cannot be sunk
// across the backedge -- the compiler's per-thread vmcnt wait for chunk c's
// operands then structurally leaves chunk c+1's loads in flight (the R5/R11
// failure was unrolling collapsing exactly this).
// af built per wave (4x redundant VALU, ~20 us device-wide -- the price of
// independence). Probe MFMAs + ones-MFMA denominator kept (R2-proven).
// ---------------------------------------------------------------------------
__global__ __launch_bounds__(256, 2) void k_gat(const unsigned long long* __restrict__ mask,
                                                const unsigned short* __restrict__ ht,
                                                const float* __restrict__ Etab,
                                                const unsigned short* __restrict__ FbfF,
                                                const unsigned short* __restrict__ FbfF2,
                                                const float* __restrict__ bias,
                                                float* __restrict__ out) {
  const int tid = threadIdx.x;
  const int wave = tid >> 6;
  const int lane = tid & 63;
  const int quad = lane >> 4;
  const int m = lane & 15;
  const int rowbase = blockIdx.x * 16;
  const int row = rowbase + m;

  // ---- runtime layout probes (exact in bf16/fp32) ----
  bf16x8 pm, pinv, pones;
  #pragma unroll
  for (int jj = 0; jj < 8; ++jj) {
    pm[jj] = (__bf16)(float)m;
    pinv[jj] = (__bf16)0.03125f;
    pones[jj] = (__bf16)1.0f;
  }
  f32x4 z = {0.f, 0.f, 0.f, 0.f};
  f32x4 rp = __builtin_amdgcn_mfma_f32_16x16x32_bf16(pm, pinv, z, 0, 0, 0);
  f32x4 cp = __builtin_amdgcn_mfma_f32_16x16x32_bf16(pinv, pm, z, 0, 0, 0);
  int rowmap[4], colmap[4];
  #pragma unroll
  for (int r = 0; r < 4; ++r) {
    rowmap[r] = ((int)(rp[r] + 0.5f)) & 15;
    colmap[r] = ((int)(cp[r] + 0.5f)) & 15;
  }

  const float E  = Etab[(size_t)row * 2];
  const float E2 = Etab[(size_t)row * 2 + 1];
  const int t0 = wave * 2, t1 = wave * 2 + 1;

  // ---- operand base pointers ----
  const unsigned long long* mp = mask + (size_t)row * 128;          // [c]
  const unsigned short* fF = FbfF + quad * 8;                       // +c*64(+32)
  const unsigned short* fG = FbfF2 + quad * 8;
  const unsigned short* hb0 = ht + (size_t)(t0 * 16 + m) * NN + quad * 8;
  const unsigned short* hb1 = ht + (size_t)(t1 * 16 + m) * NN + quad * 8;

  f32x4 acc0 = z, acc1 = z, den = z;

  // ---- prologue: chunk 0 operands ----
  unsigned long long mk_n = mp[0];
  u32x4 F0_n = *(const u32x4*)(fF);
  u32x4 F1_n = *(const u32x4*)(fF + 32);
  u32x4 G0_n = *(const u32x4*)(fG);
  u32x4 G1_n = *(const u32x4*)(fG + 32);
  u32x4 B00_n = *(const u32x4*)(hb0);
  u32x4 B01_n = *(const u32x4*)(hb0 + 32);
  u32x4 B10_n = *(const u32x4*)(hb1);
  u32x4 B11_n = *(const u32x4*)(hb1 + 32);

  #pragma unroll 1
  for (int c = 0; c < 128; ++c) {
    // rotate: cur <- next (loop-carried PHIs pin the pipeline)
    unsigned long long mk = mk_n;
    u32x4 F0 = F0_n, F1 = F1_n, G0 = G0_n, G1 = G1_n;
    u32x4 B00 = B00_n, B01 = B01_n, B10 = B10_n, B11 = B11_n;

    // issue next chunk's loads FIRST (branchless clamp; redundant at c=127)
    const int cn = (c + 1 < 128) ? (c + 1) : 127;
    const int o = cn * 64;
    mk_n = mp[cn];
    F0_n = *(const u32x4*)(fF + o);
    F1_n = *(const u32x4*)(fF + o + 32);
    G0_n = *(const u32x4*)(fG + o);
    G1_n = *(const u32x4*)(fG + o + 32);
    B00_n = *(const u32x4*)(hb0 + o);
    B01_n = *(const u32x4*)(hb0 + o + 32);
    B10_n = *(const u32x4*)(hb1 + o);
    B11_n = *(const u32x4*)(hb1 + o + 32);

    // compute chunk c (waits only on cur operands; next stays in flight)
    #pragma unroll
    for (int k32 = 0; k32 < 2; ++k32) {
      const unsigned mb = (unsigned)(mk >> (k32 * 32 + quad * 8)) & 0xffu;
      const u32x4 Fq = k32 ? F1 : F0;
      const u32x4 Gq = k32 ? G1 : G0;

      bf16x8 af;
      #pragma unroll
      for (int p = 0; p < 4; ++p) {
        const unsigned fp = Fq[p], gp = Gq[p];
        const float Flo = __builtin_bit_cast(float, fp << 16);
        const float Fhi = __builtin_bit_cast(float, fp & 0xffff0000u);
        const float Glo = __builtin_bit_cast(float, gp << 16);
        const float Ghi = __builtin_bit_cast(float, gp & 0xffff0000u);
        const float wlo = fmaxf(E * Flo, E2 * Glo);
        const float whi = fmaxf(E * Fhi, E2 * Ghi);
        af[2 * p]     = ((mb >> (2 * p)) & 1u)     ? (__bf16)wlo : (__bf16)0.0f;
        af[2 * p + 1] = ((mb >> (2 * p + 1)) & 1u) ? (__bf16)whi : (__bf16)0.0f;
      }

      const bf16x8 b0 = __builtin_bit_cast(bf16x8, k32 ? B01 : B00);
      const bf16x8 b1 = __builtin_bit_cast(bf16x8, k32 ? B11 : B10);
      acc0 = __builtin_amdgcn_mfma_f32_16x16x32_bf16(af, b0, acc0, 0, 0, 0);
      acc1 = __builtin_amdgcn_mfma_f32_16x16x32_bf16(af, b1, acc1, 0, 0, 0);
      den  = __builtin_amdgcn_mfma_f32_16x16x32_bf16(af, pones, den, 0, 0, 0);
    }
  }

  // ---- epilogue: wave-private rows x cols, direct store ----
  #pragma unroll
  for (int r = 0; r < 4; ++r) {
    const float inv = 1.0f / den[r];
    const int orow = rowbase + rowmap[r];
    const int c0 = t0 * 16 + colmap[r];
    const int c1 = t1 * 16 + colmap[r];
    out[(size_t)orow * FOUT + c0] = acc0[r] * inv + bias[c0];
    out[(size_t)orow * FOUT + c1] = acc1[r] * inv + bias[c1];
  }
}

// ---------------------------------------------------------------------------
extern "C" void kernel_launch(void* const* d_in, const int* in_sizes, int n_in,
                              void* d_out, int out_size, void* d_ws, size_t ws_size,
                              hipStream_t stream) {
  const float* x    = (const float*)d_in[0];
  const int*   adj  = (const int*)d_in[1];
  const float* W    = (const float*)d_in[2];
  const float* a1   = (const float*)d_in[3];
  const float* a2   = (const float*)d_in[4];
  const float* bias = (const float*)d_in[5];
  float* out = (float*)d_out;

  char* ws = (char*)d_ws;
  unsigned long long* maskq = (unsigned long long*)ws;               // 8 MB
  unsigned short* ht = (unsigned short*)(ws + (size_t)8 * 1024 * 1024);  // 2 MB
  float* Etab = (float*)(ws + (size_t)10 * 1024 * 1024);             // 64 KB
  unsigned short* FbfF =
      (unsigned short*)(ws + (size_t)10 * 1024 * 1024 + 64 * 1024);  // 16 KB
  unsigned short* FbfF2 = FbfF + NN;                                 // 16 KB

  k_pack<<<2048, 256, 0, stream>>>(adj, maskq);
  k_hw<<<NN / 8, 256, 0, stream>>>(x, W, a1, a2, ht, Etab, FbfF, FbfF2);
  k_gat<<<NN / 16, 256, 0, stream>>>(maskq, ht, Etab, FbfF, FbfF2, bias, out);
}